// Round 4
// baseline (535.436 us; speedup 1.0000x reference)
//
#include <hip/hip_runtime.h>
#include <math.h>

#define N_NODES 100000
#define N_EDGES 1600000
#define F_INDIM 256
#define HID 64
#define NCLS 40
#define NB_SCAN 391   // ceil(N_NODES/256)

typedef __attribute__((ext_vector_type(8))) short short8;
typedef __attribute__((ext_vector_type(4))) float floatx4;

// ---- bf16 helpers (RNE) ----
__device__ __forceinline__ unsigned short f2bf(float f) {
  unsigned u = __float_as_uint(f);
  unsigned r = (u + 0x7FFFu + ((u >> 16) & 1u)) >> 16;
  return (unsigned short)r;
}
__device__ __forceinline__ float bf2f(unsigned short h) {
  return __uint_as_float(((unsigned)h) << 16);
}

// ---------------- degree / norm / CSR build ----------------

__global__ __launch_bounds__(256) void k_zero_deg(int* __restrict__ degi) {
  int i = blockIdx.x * 256 + threadIdx.x;
  if (i < N_NODES) degi[i] = 0;
}

__global__ __launch_bounds__(256) void k_count(const int* __restrict__ col,
                                               int* __restrict__ degi) {
  int e = blockIdx.x * 256 + threadIdx.x;
  if (e < N_EDGES) atomicAdd(&degi[col[e]], 1);
}

__global__ __launch_bounds__(256) void k_dis(const int* __restrict__ degi,
                                             float* __restrict__ dis,
                                             int* __restrict__ start) {
  int i = blockIdx.x * 256 + threadIdx.x;
  if (i < N_NODES) dis[i] = rsqrtf((float)(degi[i] + 1));  // +1 self-loop
  if (i == 0) start[N_NODES] = N_EDGES;
}

__global__ __launch_bounds__(256) void k_scan1(const int* __restrict__ degi,
                                               int* __restrict__ start,
                                               int* __restrict__ bsum) {
  __shared__ int s[256];
  const int t = threadIdx.x;
  const int i = blockIdx.x * 256 + t;
  int v = (i < N_NODES) ? degi[i] : 0;
  s[t] = v;
  __syncthreads();
#pragma unroll
  for (int off = 1; off < 256; off <<= 1) {
    int u = (t >= off) ? s[t - off] : 0;
    __syncthreads();
    s[t] += u;
    __syncthreads();
  }
  if (i < N_NODES) start[i] = s[t] - v;
  if (t == 255) bsum[blockIdx.x] = s[255];
}

__global__ __launch_bounds__(512) void k_scan2(const int* __restrict__ bsum,
                                               int* __restrict__ bsumS) {
  __shared__ int s[512];
  const int t = threadIdx.x;
  int v = (t < NB_SCAN) ? bsum[t] : 0;
  s[t] = v;
  __syncthreads();
#pragma unroll
  for (int off = 1; off < 512; off <<= 1) {
    int u = (t >= off) ? s[t - off] : 0;
    __syncthreads();
    s[t] += u;
    __syncthreads();
  }
  if (t < NB_SCAN) bsumS[t] = s[t] - v;
}

__global__ __launch_bounds__(256) void k_scan3(int* __restrict__ start,
                                               int* __restrict__ cursor,
                                               const int* __restrict__ bsumS) {
  int i = blockIdx.x * 256 + threadIdx.x;
  if (i < N_NODES) {
    int val = start[i] + bsumS[blockIdx.x];
    start[i] = val;
    cursor[i] = val;
  }
}

// bucket edges by destination: esrc[pos] = src  (norm recomputed from dis in aggs)
__global__ __launch_bounds__(256) void k_build(const int* __restrict__ row,
                                               const int* __restrict__ col,
                                               int* __restrict__ cursor,
                                               int* __restrict__ esrc) {
  int e = blockIdx.x * 256 + threadIdx.x;
  if (e >= N_EDGES) return;
  int r = row[e];
  int c = col[e];
  int pos = atomicAdd(&cursor[c], 1);
  esrc[pos] = r;
}

// ---------------- GEMM1 (MFMA): h1b = bf16(x @ W1) ----------------
// 64 rows/block, 4 waves; each wave 16 rows x 64 cols via 4x mfma_16x16x32_bf16.
// W1^T staged to LDS once (bf16, stride 264), X tiles of 64x32 per K-chunk.

#define KP 264   // padded k-stride for wt
#define XP 40    // padded k-stride for xs

__global__ __launch_bounds__(256) void k_gemm1(const float* __restrict__ x,
                                               const float* __restrict__ W1,
                                               unsigned short* __restrict__ h1b) {
  __shared__ unsigned short wt[HID * KP];   // wt[n][k] = bf16(W1[k][n])
  __shared__ unsigned short xs[64 * XP];    // xs[r][k] for current chunk
  const int tid = threadIdx.x;
  const int lane = tid & 63;
  const int w = tid >> 6;           // wave id: rows w*16..w*16+15
  const int quad = lane >> 4;
  const int l15 = lane & 15;
  const int rowBase = blockIdx.x * 64;

  // stage W1^T: 256x64 fp32 -> wt[n][k] bf16
#pragma unroll
  for (int i = 0; i < 16; ++i) {
    int f = tid + 256 * i;          // 4096 float4-groups
    int k = f >> 4;
    int n0 = (f & 15) * 4;
    float4 v = *(const float4*)&W1[(size_t)k * HID + n0];
    wt[(n0 + 0) * KP + k] = f2bf(v.x);
    wt[(n0 + 1) * KP + k] = f2bf(v.y);
    wt[(n0 + 2) * KP + k] = f2bf(v.z);
    wt[(n0 + 3) * KP + k] = f2bf(v.w);
  }

  floatx4 acc[4];
#pragma unroll
  for (int c = 0; c < 4; ++c) acc[c] = (floatx4){0.f, 0.f, 0.f, 0.f};

  for (int kc = 0; kc < F_INDIM; kc += 32) {
    // stage X tile 64 rows x 32 k (fp32 -> bf16)
#pragma unroll
    for (int i = 0; i < 2; ++i) {
      int f = tid + 256 * i;        // 512 float4
      int r = f >> 3;
      int q = f & 7;
      int gr = rowBase + r;
      float4 v = make_float4(0.f, 0.f, 0.f, 0.f);
      if (gr < N_NODES) v = *(const float4*)&x[(size_t)gr * F_INDIM + kc + q * 4];
      ushort4 o;
      o.x = f2bf(v.x); o.y = f2bf(v.y); o.z = f2bf(v.z); o.w = f2bf(v.w);
      *(ushort4*)&xs[r * XP + q * 4] = o;
    }
    __syncthreads();

    // A fragment: rows w*16+l15, k = quad*8..+7
    const short8 a = *(const short8*)&xs[(w * 16 + l15) * XP + quad * 8];
#pragma unroll
    for (int c = 0; c < 4; ++c) {
      const short8 b = *(const short8*)&wt[(c * 16 + l15) * KP + kc + quad * 8];
      acc[c] = __builtin_amdgcn_mfma_f32_16x16x32_bf16(a, b, acc[c], 0, 0, 0);
    }
    __syncthreads();
  }

  // epilogue: C/D layout col=lane&15, row=quad*4+reg
#pragma unroll
  for (int c = 0; c < 4; ++c) {
#pragma unroll
    for (int reg = 0; reg < 4; ++reg) {
      int gr = rowBase + w * 16 + quad * 4 + reg;
      if (gr < N_NODES)
        h1b[(size_t)gr * HID + c * 16 + l15] = f2bf(acc[c][reg]);
    }
  }
}

// ---------------- agg1: out1 = dis^2*h1 + sum dis[s]*dis[n]*h1[s] ----------------
// one 64-lane wave per node, lane = feature; x4 unrolled gathers.

__global__ __launch_bounds__(256) void k_agg1(const int* __restrict__ esrc,
                                              const int* __restrict__ start,
                                              const float* __restrict__ dis,
                                              const unsigned short* __restrict__ h1b,
                                              float* __restrict__ out1) {
  int gid = blockIdx.x * 256 + threadIdx.x;
  int wid = gid >> 6;
  int lane = gid & 63;
  if (wid >= N_NODES) return;
  int s0 = start[wid];
  int e0 = start[wid + 1];
  float d = dis[wid];
  float acc = d * d * bf2f(h1b[(size_t)wid * HID + lane]);
  int i = s0;
  for (; i + 4 <= e0; i += 4) {
    int sa = esrc[i], sb = esrc[i + 1], sc = esrc[i + 2], sd = esrc[i + 3];
    float da = dis[sa], db = dis[sb], dc = dis[sc], dd = dis[sd];
    float va = bf2f(h1b[(size_t)sa * HID + lane]);
    float vb = bf2f(h1b[(size_t)sb * HID + lane]);
    float vc = bf2f(h1b[(size_t)sc * HID + lane]);
    float vd = bf2f(h1b[(size_t)sd * HID + lane]);
    acc += d * (da * va + db * vb + dc * vc + dd * vd);
  }
  for (; i < e0; ++i) {
    int sa = esrc[i];
    acc += d * dis[sa] * bf2f(h1b[(size_t)sa * HID + lane]);
  }
  out1[(size_t)wid * HID + lane] = acc;
}

// ---------------- GEMM2: gb = bf16(relu(out1 + b1) @ W2), rows padded to 64 ----------

__global__ __launch_bounds__(256) void k_gemm2(const float* __restrict__ out1,
                                               const float* __restrict__ W2,
                                               const float* __restrict__ b1,
                                               unsigned short* __restrict__ gb) {
  __shared__ float xs[128 * 68];
  __shared__ float ws2[64 * NCLS];
  const int tid = threadIdx.x;
  const int c0 = (tid & 7) * 5;
  const int r0 = (tid >> 3) * 4;
  const int rowBase = blockIdx.x * 128;

#pragma unroll
  for (int i = 0; i < 3; ++i) {
    int f = tid + 256 * i;
    if (f < 640) *(float4*)&ws2[f * 4] = *(const float4*)&W2[f * 4];
  }
#pragma unroll
  for (int i = 0; i < 8; ++i) {
    int f = tid + 256 * i;
    int r = f >> 4, kq = f & 15;
    int gr = rowBase + r;
    float4 v = make_float4(0.f, 0.f, 0.f, 0.f);
    if (gr < N_NODES) {
      v = *(const float4*)&out1[(size_t)gr * HID + kq * 4];
      float4 bv = *(const float4*)&b1[kq * 4];
      v.x = fmaxf(v.x + bv.x, 0.f);
      v.y = fmaxf(v.y + bv.y, 0.f);
      v.z = fmaxf(v.z + bv.z, 0.f);
      v.w = fmaxf(v.w + bv.w, 0.f);
    }
    *(float4*)&xs[r * 68 + kq * 4] = v;
  }
  __syncthreads();

  float acc[4][5];
#pragma unroll
  for (int j = 0; j < 4; ++j)
#pragma unroll
    for (int i = 0; i < 5; ++i) acc[j][i] = 0.0f;

  for (int k0 = 0; k0 < HID; k0 += 4) {
    float4 xv[4];
#pragma unroll
    for (int j = 0; j < 4; ++j) xv[j] = *(const float4*)&xs[(r0 + j) * 68 + k0];
#pragma unroll
    for (int kk = 0; kk < 4; ++kk) {
      const float* wrow = &ws2[(k0 + kk) * NCLS + c0];
      float w0 = wrow[0], w1 = wrow[1], w2 = wrow[2], w3 = wrow[3], w4 = wrow[4];
#pragma unroll
      for (int j = 0; j < 4; ++j) {
        const float xk = ((const float*)&xv[j])[kk];
        acc[j][0] += xk * w0;
        acc[j][1] += xk * w1;
        acc[j][2] += xk * w2;
        acc[j][3] += xk * w3;
        acc[j][4] += xk * w4;
      }
    }
  }

#pragma unroll
  for (int j = 0; j < 4; ++j) {
    int gr = rowBase + r0 + j;
    if (gr < N_NODES) {
#pragma unroll
      for (int i = 0; i < 5; ++i)
        gb[(size_t)gr * 64 + c0 + i] = f2bf(acc[j][i]);  // stride 64 (padded)
    }
  }
}

// ---------------- agg2 + log_softmax fused: one wave per node ----------------

__global__ __launch_bounds__(256) void k_agg2ls(const int* __restrict__ esrc,
                                                const int* __restrict__ start,
                                                const float* __restrict__ dis,
                                                const unsigned short* __restrict__ gb,
                                                const float* __restrict__ b2,
                                                float* __restrict__ out) {
  int gid = blockIdx.x * 256 + threadIdx.x;
  int node = gid >> 6;
  int lane = gid & 63;
  if (node >= N_NODES) return;
  const bool act = lane < NCLS;
  int s0 = start[node];
  int e0 = start[node + 1];
  float d = dis[node];
  float acc = act ? d * d * bf2f(gb[(size_t)node * 64 + lane]) : 0.f;
  int i = s0;
  for (; i + 4 <= e0; i += 4) {
    int sa = esrc[i], sb = esrc[i + 1], sc = esrc[i + 2], sd = esrc[i + 3];
    float da = dis[sa], db = dis[sb], dc = dis[sc], dd = dis[sd];
    float va = bf2f(gb[(size_t)sa * 64 + lane]);
    float vb = bf2f(gb[(size_t)sb * 64 + lane]);
    float vc = bf2f(gb[(size_t)sc * 64 + lane]);
    float vd = bf2f(gb[(size_t)sd * 64 + lane]);
    acc += d * (da * va + db * vb + dc * vc + dd * vd);
  }
  for (; i < e0; ++i) {
    int sa = esrc[i];
    acc += d * dis[sa] * bf2f(gb[(size_t)sa * 64 + lane]);
  }
  // + b2, then log_softmax over lanes 0..39
  float val = act ? acc + b2[lane] : 0.f;
  float m = act ? val : -INFINITY;
#pragma unroll
  for (int off = 32; off > 0; off >>= 1) m = fmaxf(m, __shfl_xor(m, off));
  float ex = act ? expf(val - m) : 0.f;
  float s = ex;
#pragma unroll
  for (int off = 32; off > 0; off >>= 1) s += __shfl_xor(s, off);
  float ls = logf(s);
  if (act) out[(size_t)node * NCLS + lane] = val - m - ls;
}

// ---------------- launch ----------------

extern "C" void kernel_launch(void* const* d_in, const int* in_sizes, int n_in,
                              void* d_out, int out_size, void* d_ws, size_t ws_size,
                              hipStream_t stream) {
  const float* x  = (const float*)d_in[0];
  const int*   ei = (const int*)d_in[1];
  const float* W1 = (const float*)d_in[2];
  const float* b1 = (const float*)d_in[3];
  const float* W2 = (const float*)d_in[4];
  const float* b2 = (const float*)d_in[5];
  float* out = (float*)d_out;

  const int* row = ei;             // edge_index[0] = src
  const int* col = ei + N_EDGES;   // edge_index[1] = dst

  // workspace layout
  int*            esrc   = (int*)d_ws;                           // E ints    (6.4 MB)
  unsigned short* h1b    = (unsigned short*)(esrc + N_EDGES);    // N*64 bf16 (12.8 MB)
  float*          out1   = (float*)(h1b + (size_t)N_NODES * HID);// N*64 fp32 (25.6 MB)
  float*          dis    = out1 + (size_t)N_NODES * HID;         // N
  int*            degi   = (int*)(dis + N_NODES);                // N
  int*            start  = degi + N_NODES;                       // N+1
  int*            cursor = start + N_NODES + 1;                  // N
  int*            bsum   = cursor + N_NODES;                     // NB_SCAN
  int*            bsumS  = bsum + NB_SCAN;                       // NB_SCAN
  unsigned short* gb     = h1b;                                  // N*64 bf16, reuse

  const int gridN = (N_NODES + 255) / 256;     // 391
  const int gridE = (N_EDGES + 255) / 256;

  k_zero_deg<<<gridN, 256, 0, stream>>>(degi);
  k_count<<<gridE, 256, 0, stream>>>(col, degi);
  k_dis<<<gridN, 256, 0, stream>>>(degi, dis, start);
  k_scan1<<<gridN, 256, 0, stream>>>(degi, start, bsum);
  k_scan2<<<1, 512, 0, stream>>>(bsum, bsumS);
  k_scan3<<<gridN, 256, 0, stream>>>(start, cursor, bsumS);
  k_build<<<gridE, 256, 0, stream>>>(row, col, cursor, esrc);

  k_gemm1<<<(N_NODES + 63) / 64, 256, 0, stream>>>(x, W1, h1b);
  k_agg1<<<(N_NODES * 64 + 255) / 256, 256, 0, stream>>>(esrc, start, dis, h1b, out1);

  k_gemm2<<<(N_NODES + 127) / 128, 256, 0, stream>>>(out1, W2, b1, gb);
  k_agg2ls<<<(N_NODES * 64 + 255) / 256, 256, 0, stream>>>(esrc, start, dis, gb, b2, out);
}

// Round 5
// 405.547 us; speedup vs baseline: 1.3203x; 1.3203x over previous
//
#include <hip/hip_runtime.h>
#include <math.h>

#define N_NODES 100000
#define N_EDGES 1600000
#define F_INDIM 256
#define HID 64
#define NCLS 40
#define NB_SCAN 391      // ceil(N_NODES/256)
#define NBKT 196         // ceil(N_NODES/512) coarse buckets of 512 dst nodes
#define BKT_CAP 10240    // per-bucket capacity (mean 8192, sigma~90 -> 22 sigma slack)
#define EPB 8192         // edges per block in k_binA

typedef __attribute__((ext_vector_type(8))) short short8;
typedef __attribute__((ext_vector_type(4))) float floatx4;

// ---- bf16 helpers (RNE) ----
__device__ __forceinline__ unsigned short f2bf(float f) {
  unsigned u = __float_as_uint(f);
  unsigned r = (u + 0x7FFFu + ((u >> 16) & 1u)) >> 16;
  return (unsigned short)r;
}
__device__ __forceinline__ float bf2f(unsigned short h) {
  return __uint_as_float(((unsigned)h) << 16);
}

// ---------------- tiny init: zero bucket cursors, set scan sentinel ----------------

__global__ __launch_bounds__(256) void k_zero(int* __restrict__ gcur,
                                              int* __restrict__ start) {
  int t = threadIdx.x;
  if (t < NBKT) gcur[t] = 0;
  if (t == 0) start[N_NODES] = N_EDGES;
}

// ---------------- phase A: coarse-bucket edges with clustered writes ----------------
// bucket = dst >> 9. Each block reserves one contiguous run per bucket, so its
// writes cluster into ~196 short runs (L2-resident) instead of random lines.

__global__ __launch_bounds__(256) void k_binA(const int* __restrict__ row,
                                              const int* __restrict__ col,
                                              int* __restrict__ gcur,
                                              unsigned int* __restrict__ bktdata) {
  __shared__ int hist[NBKT];
  __shared__ int cur[NBKT];
  __shared__ int gbase[NBKT];
  const int t = threadIdx.x;
  const int e0 = blockIdx.x * EPB;
  const int n = min(EPB, N_EDGES - e0);
  if (t < NBKT) hist[t] = 0;
  __syncthreads();
  for (int i = t; i < n; i += 256) atomicAdd(&hist[col[e0 + i] >> 9], 1);
  __syncthreads();
  if (t < NBKT) {
    cur[t] = 0;
    int h = hist[t];
    gbase[t] = (h > 0) ? atomicAdd(&gcur[t], h) : 0;
  }
  __syncthreads();
  for (int i = t; i < n; i += 256) {
    int c = col[e0 + i];
    int r = row[e0 + i];
    int b = c >> 9;
    int p = atomicAdd(&cur[b], 1);
    bktdata[(size_t)b * BKT_CAP + gbase[b] + p] =
        ((unsigned)(c & 511) << 17) | (unsigned)r;
  }
}

// ---------------- phase B1: per-bucket histogram -> dense degi + dis ----------------

__global__ __launch_bounds__(256) void k_histdis(const int* __restrict__ gcur,
                                                 const unsigned int* __restrict__ bktdata,
                                                 int* __restrict__ degi,
                                                 float* __restrict__ dis) {
  __shared__ int h[512];
  const int b = blockIdx.x, t = threadIdx.x;
  h[t] = 0; h[t + 256] = 0;
  __syncthreads();
  const int cnt = gcur[b];
  const unsigned int* p = bktdata + (size_t)b * BKT_CAP;
  for (int i = t; i < cnt; i += 256) atomicAdd(&h[p[i] >> 17], 1);
  __syncthreads();
  int n0 = b * 512 + t;
  if (n0 < N_NODES) { degi[n0] = h[t]; dis[n0] = rsqrtf((float)(h[t] + 1)); }
  int n1 = n0 + 256;
  if (n1 < N_NODES) { degi[n1] = h[t + 256]; dis[n1] = rsqrtf((float)(h[t + 256] + 1)); }
}

// ---------------- scans over degi -> start ----------------

__global__ __launch_bounds__(256) void k_scan1(const int* __restrict__ degi,
                                               int* __restrict__ start,
                                               int* __restrict__ bsum) {
  __shared__ int s[256];
  const int t = threadIdx.x;
  const int i = blockIdx.x * 256 + t;
  int v = (i < N_NODES) ? degi[i] : 0;
  s[t] = v;
  __syncthreads();
#pragma unroll
  for (int off = 1; off < 256; off <<= 1) {
    int u = (t >= off) ? s[t - off] : 0;
    __syncthreads();
    s[t] += u;
    __syncthreads();
  }
  if (i < N_NODES) start[i] = s[t] - v;
  if (t == 255) bsum[blockIdx.x] = s[255];
}

__global__ __launch_bounds__(512) void k_scan2(const int* __restrict__ bsum,
                                               int* __restrict__ bsumS) {
  __shared__ int s[512];
  const int t = threadIdx.x;
  int v = (t < NB_SCAN) ? bsum[t] : 0;
  s[t] = v;
  __syncthreads();
#pragma unroll
  for (int off = 1; off < 512; off <<= 1) {
    int u = (t >= off) ? s[t - off] : 0;
    __syncthreads();
    s[t] += u;
    __syncthreads();
  }
  if (t < NB_SCAN) bsumS[t] = s[t] - v;
}

__global__ __launch_bounds__(256) void k_scan3(int* __restrict__ start,
                                               const int* __restrict__ bsumS) {
  int i = blockIdx.x * 256 + threadIdx.x;
  if (i < N_NODES) start[i] += bsumS[blockIdx.x];
}

// ---------------- phase B2: final placement, writes confined to 32KB window ------

__global__ __launch_bounds__(256) void k_place(const int* __restrict__ gcur,
                                               const unsigned int* __restrict__ bktdata,
                                               const int* __restrict__ start,
                                               int* __restrict__ esrc) {
  __shared__ int cur[512];
  const int b = blockIdx.x, t = threadIdx.x;
  cur[t] = 0; cur[t + 256] = 0;
  __syncthreads();
  const int cnt = gcur[b];
  const unsigned int* p = bktdata + (size_t)b * BKT_CAP;
  const int nbase = b * 512;
  for (int i = t; i < cnt; i += 256) {
    unsigned u = p[i];
    int ld = u >> 17;
    int src = u & 0x1FFFF;
    int pos = start[nbase + ld] + atomicAdd(&cur[ld], 1);
    esrc[pos] = src;
  }
}

// ---------------- GEMM1 (MFMA): h1b = bf16(x @ W1) ----------------

#define KP 264   // padded k-stride for wt
#define XP 40    // padded k-stride for xs

__global__ __launch_bounds__(256) void k_gemm1(const float* __restrict__ x,
                                               const float* __restrict__ W1,
                                               unsigned short* __restrict__ h1b) {
  __shared__ unsigned short wt[HID * KP];   // wt[n][k] = bf16(W1[k][n])
  __shared__ unsigned short xs[64 * XP];    // xs[r][k] for current chunk
  const int tid = threadIdx.x;
  const int lane = tid & 63;
  const int w = tid >> 6;
  const int quad = lane >> 4;
  const int l15 = lane & 15;
  const int rowBase = blockIdx.x * 64;

#pragma unroll
  for (int i = 0; i < 16; ++i) {
    int f = tid + 256 * i;
    int k = f >> 4;
    int n0 = (f & 15) * 4;
    float4 v = *(const float4*)&W1[(size_t)k * HID + n0];
    wt[(n0 + 0) * KP + k] = f2bf(v.x);
    wt[(n0 + 1) * KP + k] = f2bf(v.y);
    wt[(n0 + 2) * KP + k] = f2bf(v.z);
    wt[(n0 + 3) * KP + k] = f2bf(v.w);
  }

  floatx4 acc[4];
#pragma unroll
  for (int c = 0; c < 4; ++c) acc[c] = (floatx4){0.f, 0.f, 0.f, 0.f};

  for (int kc = 0; kc < F_INDIM; kc += 32) {
#pragma unroll
    for (int i = 0; i < 2; ++i) {
      int f = tid + 256 * i;
      int r = f >> 3;
      int q = f & 7;
      int gr = rowBase + r;
      float4 v = make_float4(0.f, 0.f, 0.f, 0.f);
      if (gr < N_NODES) v = *(const float4*)&x[(size_t)gr * F_INDIM + kc + q * 4];
      ushort4 o;
      o.x = f2bf(v.x); o.y = f2bf(v.y); o.z = f2bf(v.z); o.w = f2bf(v.w);
      *(ushort4*)&xs[r * XP + q * 4] = o;
    }
    __syncthreads();

    const short8 a = *(const short8*)&xs[(w * 16 + l15) * XP + quad * 8];
#pragma unroll
    for (int c = 0; c < 4; ++c) {
      const short8 b = *(const short8*)&wt[(c * 16 + l15) * KP + kc + quad * 8];
      acc[c] = __builtin_amdgcn_mfma_f32_16x16x32_bf16(a, b, acc[c], 0, 0, 0);
    }
    __syncthreads();
  }

#pragma unroll
  for (int c = 0; c < 4; ++c) {
#pragma unroll
    for (int reg = 0; reg < 4; ++reg) {
      int gr = rowBase + w * 16 + quad * 4 + reg;
      if (gr < N_NODES)
        h1b[(size_t)gr * HID + c * 16 + l15] = f2bf(acc[c][reg]);
    }
  }
}

// ---------------- agg1: out1 = dis^2*h1 + sum dis[s]*dis[n]*h1[s]  (x8 unroll) ----

__global__ __launch_bounds__(256) void k_agg1(const int* __restrict__ esrc,
                                              const int* __restrict__ start,
                                              const float* __restrict__ dis,
                                              const unsigned short* __restrict__ h1b,
                                              float* __restrict__ out1) {
  int gid = blockIdx.x * 256 + threadIdx.x;
  int wid = gid >> 6;
  int lane = gid & 63;
  if (wid >= N_NODES) return;
  int s0 = start[wid];
  int e0 = start[wid + 1];
  float d = dis[wid];
  float acc = d * d * bf2f(h1b[(size_t)wid * HID + lane]);
  int i = s0;
  for (; i + 8 <= e0; i += 8) {
    int s_[8];
    float dv[8], hv[8];
#pragma unroll
    for (int j = 0; j < 8; ++j) s_[j] = esrc[i + j];
#pragma unroll
    for (int j = 0; j < 8; ++j) dv[j] = dis[s_[j]];
#pragma unroll
    for (int j = 0; j < 8; ++j) hv[j] = bf2f(h1b[(size_t)s_[j] * HID + lane]);
    float t = 0.f;
#pragma unroll
    for (int j = 0; j < 8; ++j) t += dv[j] * hv[j];
    acc += d * t;
  }
  for (; i < e0; ++i) {
    int sa = esrc[i];
    acc += d * dis[sa] * bf2f(h1b[(size_t)sa * HID + lane]);
  }
  out1[(size_t)wid * HID + lane] = acc;
}

// ---------------- GEMM2: gb = bf16(relu(out1 + b1) @ W2), rows padded to 64 ------

__global__ __launch_bounds__(256) void k_gemm2(const float* __restrict__ out1,
                                               const float* __restrict__ W2,
                                               const float* __restrict__ b1,
                                               unsigned short* __restrict__ gb) {
  __shared__ float xs[128 * 68];
  __shared__ float ws2[64 * NCLS];
  const int tid = threadIdx.x;
  const int c0 = (tid & 7) * 5;
  const int r0 = (tid >> 3) * 4;
  const int rowBase = blockIdx.x * 128;

#pragma unroll
  for (int i = 0; i < 3; ++i) {
    int f = tid + 256 * i;
    if (f < 640) *(float4*)&ws2[f * 4] = *(const float4*)&W2[f * 4];
  }
#pragma unroll
  for (int i = 0; i < 8; ++i) {
    int f = tid + 256 * i;
    int r = f >> 4, kq = f & 15;
    int gr = rowBase + r;
    float4 v = make_float4(0.f, 0.f, 0.f, 0.f);
    if (gr < N_NODES) {
      v = *(const float4*)&out1[(size_t)gr * HID + kq * 4];
      float4 bv = *(const float4*)&b1[kq * 4];
      v.x = fmaxf(v.x + bv.x, 0.f);
      v.y = fmaxf(v.y + bv.y, 0.f);
      v.z = fmaxf(v.z + bv.z, 0.f);
      v.w = fmaxf(v.w + bv.w, 0.f);
    }
    *(float4*)&xs[r * 68 + kq * 4] = v;
  }
  __syncthreads();

  float acc[4][5];
#pragma unroll
  for (int j = 0; j < 4; ++j)
#pragma unroll
    for (int i = 0; i < 5; ++i) acc[j][i] = 0.0f;

  for (int k0 = 0; k0 < HID; k0 += 4) {
    float4 xv[4];
#pragma unroll
    for (int j = 0; j < 4; ++j) xv[j] = *(const float4*)&xs[(r0 + j) * 68 + k0];
#pragma unroll
    for (int kk = 0; kk < 4; ++kk) {
      const float* wrow = &ws2[(k0 + kk) * NCLS + c0];
      float w0 = wrow[0], w1 = wrow[1], w2 = wrow[2], w3 = wrow[3], w4 = wrow[4];
#pragma unroll
      for (int j = 0; j < 4; ++j) {
        const float xk = ((const float*)&xv[j])[kk];
        acc[j][0] += xk * w0;
        acc[j][1] += xk * w1;
        acc[j][2] += xk * w2;
        acc[j][3] += xk * w3;
        acc[j][4] += xk * w4;
      }
    }
  }

#pragma unroll
  for (int j = 0; j < 4; ++j) {
    int gr = rowBase + r0 + j;
    if (gr < N_NODES) {
#pragma unroll
      for (int i = 0; i < 5; ++i)
        gb[(size_t)gr * 64 + c0 + i] = f2bf(acc[j][i]);  // stride 64 (padded)
    }
  }
}

// ---------------- agg2 + log_softmax fused (x8 unroll) ----------------

__global__ __launch_bounds__(256) void k_agg2ls(const int* __restrict__ esrc,
                                                const int* __restrict__ start,
                                                const float* __restrict__ dis,
                                                const unsigned short* __restrict__ gb,
                                                const float* __restrict__ b2,
                                                float* __restrict__ out) {
  int gid = blockIdx.x * 256 + threadIdx.x;
  int node = gid >> 6;
  int lane = gid & 63;
  if (node >= N_NODES) return;
  const bool act = lane < NCLS;
  int s0 = start[node];
  int e0 = start[node + 1];
  float d = dis[node];
  float acc = act ? d * d * bf2f(gb[(size_t)node * 64 + lane]) : 0.f;
  int i = s0;
  for (; i + 8 <= e0; i += 8) {
    int s_[8];
    float dv[8], hv[8];
#pragma unroll
    for (int j = 0; j < 8; ++j) s_[j] = esrc[i + j];
#pragma unroll
    for (int j = 0; j < 8; ++j) dv[j] = dis[s_[j]];
#pragma unroll
    for (int j = 0; j < 8; ++j) hv[j] = bf2f(gb[(size_t)s_[j] * 64 + lane]);
    float t = 0.f;
#pragma unroll
    for (int j = 0; j < 8; ++j) t += dv[j] * hv[j];
    acc += d * t;
  }
  for (; i < e0; ++i) {
    int sa = esrc[i];
    acc += d * dis[sa] * bf2f(gb[(size_t)sa * 64 + lane]);
  }
  float val = act ? acc + b2[lane] : 0.f;
  float m = act ? val : -INFINITY;
#pragma unroll
  for (int off = 32; off > 0; off >>= 1) m = fmaxf(m, __shfl_xor(m, off));
  float ex = act ? expf(val - m) : 0.f;
  float s = ex;
#pragma unroll
  for (int off = 32; off > 0; off >>= 1) s += __shfl_xor(s, off);
  float ls = logf(s);
  if (act) out[(size_t)node * NCLS + lane] = val - m - ls;
}

// ---------------- launch ----------------

extern "C" void kernel_launch(void* const* d_in, const int* in_sizes, int n_in,
                              void* d_out, int out_size, void* d_ws, size_t ws_size,
                              hipStream_t stream) {
  const float* x  = (const float*)d_in[0];
  const int*   ei = (const int*)d_in[1];
  const float* W1 = (const float*)d_in[2];
  const float* b1 = (const float*)d_in[3];
  const float* W2 = (const float*)d_in[4];
  const float* b2 = (const float*)d_in[5];
  float* out = (float*)d_out;

  const int* row = ei;             // edge_index[0] = src
  const int* col = ei + N_EDGES;   // edge_index[1] = dst

  // workspace layout (~54 MB)
  int*            esrc    = (int*)d_ws;                            // E ints     (6.4 MB)
  unsigned int*   bktdata = (unsigned int*)(esrc + N_EDGES);       // NBKT*CAP   (8.0 MB)
  unsigned short* h1b     = (unsigned short*)(bktdata + (size_t)NBKT * BKT_CAP); // 12.8 MB
  float*          out1    = (float*)(h1b + (size_t)N_NODES * HID); // N*64 fp32  (25.6 MB)
  float*          dis     = out1 + (size_t)N_NODES * HID;          // N
  int*            degi    = (int*)(dis + N_NODES);                 // N
  int*            start   = degi + N_NODES;                        // N+1
  int*            gcur    = start + N_NODES + 1;                   // NBKT
  int*            bsum    = gcur + NBKT;                           // NB_SCAN
  int*            bsumS   = bsum + NB_SCAN;                        // NB_SCAN
  unsigned short* gb      = h1b;                                   // N*64 bf16, reuse

  k_zero<<<1, 256, 0, stream>>>(gcur, start);
  k_binA<<<(N_EDGES + EPB - 1) / EPB, 256, 0, stream>>>(row, col, gcur, bktdata);
  k_histdis<<<NBKT, 256, 0, stream>>>(gcur, bktdata, degi, dis);
  k_scan1<<<NB_SCAN, 256, 0, stream>>>(degi, start, bsum);
  k_scan2<<<1, 512, 0, stream>>>(bsum, bsumS);
  k_scan3<<<NB_SCAN, 256, 0, stream>>>(start, bsumS);
  k_place<<<NBKT, 256, 0, stream>>>(gcur, bktdata, start, esrc);

  k_gemm1<<<(N_NODES + 63) / 64, 256, 0, stream>>>(x, W1, h1b);
  k_agg1<<<(N_NODES * 64 + 255) / 256, 256, 0, stream>>>(esrc, start, dis, h1b, out1);

  k_gemm2<<<(N_NODES + 127) / 128, 256, 0, stream>>>(out1, W2, b1, gb);
  k_agg2ls<<<(N_NODES * 64 + 255) / 256, 256, 0, stream>>>(esrc, start, dis, gb, b2, out);
}

// Round 6
// 400.795 us; speedup vs baseline: 1.3359x; 1.0119x over previous
//
#include <hip/hip_runtime.h>
#include <math.h>

#define N_NODES 100000
#define N_EDGES 1600000
#define F_INDIM 256
#define HID 64
#define NCLS 40
#define NB_SCAN 391      // ceil(N_NODES/256)
#define NBKT 196         // ceil(N_NODES/512) coarse buckets of 512 dst nodes
#define BKT_CAP 10240    // per-bucket capacity (mean 8192 for uniform graph)
#define EPB 8192         // edges per block in k_binA

typedef __attribute__((ext_vector_type(8))) short short8;
typedef __attribute__((ext_vector_type(4))) float floatx4;

// ---- bf16 helpers (RNE) ----
__device__ __forceinline__ unsigned short f2bf(float f) {
  unsigned u = __float_as_uint(f);
  unsigned r = (u + 0x7FFFu + ((u >> 16) & 1u)) >> 16;
  return (unsigned short)r;
}
__device__ __forceinline__ float bf2f(unsigned short h) {
  return __uint_as_float(((unsigned)h) << 16);
}

// ---------------- tiny init ----------------

__global__ __launch_bounds__(256) void k_zero(int* __restrict__ gcur,
                                              int* __restrict__ start) {
  int t = threadIdx.x;
  if (t < NBKT) gcur[t] = 0;
  if (t == 0) start[N_NODES] = N_EDGES;
}

// ---------------- phase A: coarse-bucket edges, clustered writes ----------------

__global__ __launch_bounds__(256) void k_binA(const int* __restrict__ row,
                                              const int* __restrict__ col,
                                              int* __restrict__ gcur,
                                              unsigned int* __restrict__ bktdata) {
  __shared__ int hist[NBKT];
  __shared__ int cur[NBKT];
  __shared__ int gbase[NBKT];
  const int t = threadIdx.x;
  const int e0 = blockIdx.x * EPB;
  const int n = min(EPB, N_EDGES - e0);
  if (t < NBKT) hist[t] = 0;
  __syncthreads();
  for (int i = t; i < n; i += 256) atomicAdd(&hist[col[e0 + i] >> 9], 1);
  __syncthreads();
  if (t < NBKT) {
    cur[t] = 0;
    int h = hist[t];
    gbase[t] = (h > 0) ? atomicAdd(&gcur[t], h) : 0;
  }
  __syncthreads();
  for (int i = t; i < n; i += 256) {
    int c = col[e0 + i];
    int r = row[e0 + i];
    int b = c >> 9;
    int p = atomicAdd(&cur[b], 1);
    bktdata[(size_t)b * BKT_CAP + gbase[b] + p] =
        ((unsigned)(c & 511) << 17) | (unsigned)r;
  }
}

// ---------------- phase B1: per-bucket hist -> dense degi + dis ----------------

__global__ __launch_bounds__(256) void k_histdis(const int* __restrict__ gcur,
                                                 const unsigned int* __restrict__ bktdata,
                                                 int* __restrict__ degi,
                                                 float* __restrict__ dis) {
  __shared__ int h[512];
  const int b = blockIdx.x, t = threadIdx.x;
  h[t] = 0; h[t + 256] = 0;
  __syncthreads();
  const int cnt = gcur[b];
  const unsigned int* p = bktdata + (size_t)b * BKT_CAP;
  for (int i = t; i < cnt; i += 256) atomicAdd(&h[p[i] >> 17], 1);
  __syncthreads();
  int n0 = b * 512 + t;
  if (n0 < N_NODES) { degi[n0] = h[t]; dis[n0] = rsqrtf((float)(h[t] + 1)); }
  int n1 = n0 + 256;
  if (n1 < N_NODES) { degi[n1] = h[t + 256]; dis[n1] = rsqrtf((float)(h[t + 256] + 1)); }
}

// ---------------- scans ----------------

__global__ __launch_bounds__(256) void k_scan1(const int* __restrict__ degi,
                                               int* __restrict__ start,
                                               int* __restrict__ bsum) {
  __shared__ int s[256];
  const int t = threadIdx.x;
  const int i = blockIdx.x * 256 + t;
  int v = (i < N_NODES) ? degi[i] : 0;
  s[t] = v;
  __syncthreads();
#pragma unroll
  for (int off = 1; off < 256; off <<= 1) {
    int u = (t >= off) ? s[t - off] : 0;
    __syncthreads();
    s[t] += u;
    __syncthreads();
  }
  if (i < N_NODES) start[i] = s[t] - v;
  if (t == 255) bsum[blockIdx.x] = s[255];
}

__global__ __launch_bounds__(512) void k_scan2(const int* __restrict__ bsum,
                                               int* __restrict__ bsumS) {
  __shared__ int s[512];
  const int t = threadIdx.x;
  int v = (t < NB_SCAN) ? bsum[t] : 0;
  s[t] = v;
  __syncthreads();
#pragma unroll
  for (int off = 1; off < 512; off <<= 1) {
    int u = (t >= off) ? s[t - off] : 0;
    __syncthreads();
    s[t] += u;
    __syncthreads();
  }
  if (t < NB_SCAN) bsumS[t] = s[t] - v;
}

__global__ __launch_bounds__(256) void k_scan3(int* __restrict__ start,
                                               const int* __restrict__ bsumS) {
  int i = blockIdx.x * 256 + threadIdx.x;
  if (i < N_NODES) start[i] += bsumS[blockIdx.x];
}

// ---------------- phase B2: final placement ----------------

__global__ __launch_bounds__(256) void k_place(const int* __restrict__ gcur,
                                               const unsigned int* __restrict__ bktdata,
                                               const int* __restrict__ start,
                                               int* __restrict__ esrc) {
  __shared__ int cur[512];
  const int b = blockIdx.x, t = threadIdx.x;
  cur[t] = 0; cur[t + 256] = 0;
  __syncthreads();
  const int cnt = gcur[b];
  const unsigned int* p = bktdata + (size_t)b * BKT_CAP;
  const int nbase = b * 512;
  for (int i = t; i < cnt; i += 256) {
    unsigned u = p[i];
    int ld = u >> 17;
    int src = u & 0x1FFFF;
    int pos = start[nbase + ld] + atomicAdd(&cur[ld], 1);
    esrc[pos] = src;
  }
}

// ---------------- GEMM1 (MFMA): h1b = bf16(dis[row] * (x @ W1)) ----------------

#define KP 264   // padded k-stride for wt
#define XP 40    // padded k-stride for xs

__global__ __launch_bounds__(256) void k_gemm1(const float* __restrict__ x,
                                               const float* __restrict__ W1,
                                               const float* __restrict__ dis,
                                               unsigned short* __restrict__ h1b) {
  __shared__ unsigned short wt[HID * KP];   // wt[n][k] = bf16(W1[k][n])
  __shared__ unsigned short xs[64 * XP];
  const int tid = threadIdx.x;
  const int lane = tid & 63;
  const int w = tid >> 6;
  const int quad = lane >> 4;
  const int l15 = lane & 15;
  const int rowBase = blockIdx.x * 64;

#pragma unroll
  for (int i = 0; i < 16; ++i) {
    int f = tid + 256 * i;
    int k = f >> 4;
    int n0 = (f & 15) * 4;
    float4 v = *(const float4*)&W1[(size_t)k * HID + n0];
    wt[(n0 + 0) * KP + k] = f2bf(v.x);
    wt[(n0 + 1) * KP + k] = f2bf(v.y);
    wt[(n0 + 2) * KP + k] = f2bf(v.z);
    wt[(n0 + 3) * KP + k] = f2bf(v.w);
  }

  floatx4 acc[4];
#pragma unroll
  for (int c = 0; c < 4; ++c) acc[c] = (floatx4){0.f, 0.f, 0.f, 0.f};

  for (int kc = 0; kc < F_INDIM; kc += 32) {
#pragma unroll
    for (int i = 0; i < 2; ++i) {
      int f = tid + 256 * i;
      int r = f >> 3;
      int q = f & 7;
      int gr = rowBase + r;
      float4 v = make_float4(0.f, 0.f, 0.f, 0.f);
      if (gr < N_NODES) v = *(const float4*)&x[(size_t)gr * F_INDIM + kc + q * 4];
      ushort4 o;
      o.x = f2bf(v.x); o.y = f2bf(v.y); o.z = f2bf(v.z); o.w = f2bf(v.w);
      *(ushort4*)&xs[r * XP + q * 4] = o;
    }
    __syncthreads();

    const short8 a = *(const short8*)&xs[(w * 16 + l15) * XP + quad * 8];
#pragma unroll
    for (int c = 0; c < 4; ++c) {
      const short8 b = *(const short8*)&wt[(c * 16 + l15) * KP + kc + quad * 8];
      acc[c] = __builtin_amdgcn_mfma_f32_16x16x32_bf16(a, b, acc[c], 0, 0, 0);
    }
    __syncthreads();
  }

#pragma unroll
  for (int reg = 0; reg < 4; ++reg) {
    int gr = rowBase + w * 16 + quad * 4 + reg;
    if (gr < N_NODES) {
      float d = dis[gr];
#pragma unroll
      for (int c = 0; c < 4; ++c)
        h1b[(size_t)gr * HID + c * 16 + l15] = f2bf(d * acc[c][reg]);
    }
  }
}

// ---------------- agg1: ab = bf16(relu(dis[n]*(self+sum) + b1)) ----------------
// one wave per node; pre-scaled gathers -> gather+add only.

__global__ __launch_bounds__(256) void k_agg1(const int* __restrict__ esrc,
                                              const int* __restrict__ start,
                                              const float* __restrict__ dis,
                                              const unsigned short* __restrict__ h1b,
                                              const float* __restrict__ b1,
                                              unsigned short* __restrict__ ab) {
  int gid = blockIdx.x * 256 + threadIdx.x;
  int wid = gid >> 6;
  int lane = gid & 63;
  if (wid >= N_NODES) return;
  int s0 = start[wid];
  int e0 = start[wid + 1];
  float acc = bf2f(h1b[(size_t)wid * HID + lane]);   // self term (pre-scaled)
  int i = s0;
  for (; i + 8 <= e0; i += 8) {
    int s_[8];
    float hv[8];
#pragma unroll
    for (int j = 0; j < 8; ++j) s_[j] = esrc[i + j];
#pragma unroll
    for (int j = 0; j < 8; ++j) hv[j] = bf2f(h1b[(size_t)s_[j] * HID + lane]);
    float t = 0.f;
#pragma unroll
    for (int j = 0; j < 8; ++j) t += hv[j];
    acc += t;
  }
  for (; i < e0; ++i) acc += bf2f(h1b[(size_t)esrc[i] * HID + lane]);
  float val = dis[wid] * acc + b1[lane];
  ab[(size_t)wid * HID + lane] = f2bf(fmaxf(val, 0.f));
}

// ---------------- GEMM2 (MFMA): gb = bf16(dis[row] * (ab @ W2)), rows padded 64 ----
// 64 rows/block, 4 waves x 16 rows; N=40 padded to 48 (3 col-tiles), K=64.

#define AP 72    // padded k-stride

__global__ __launch_bounds__(256) void k_gemm2(const unsigned short* __restrict__ ab,
                                               const float* __restrict__ W2,
                                               const float* __restrict__ dis,
                                               unsigned short* __restrict__ gb) {
  __shared__ unsigned short as[64 * AP];
  __shared__ unsigned short w2t[48 * AP];   // w2t[n][k] = bf16(W2[k][n]), 0-pad n>=40
  const int tid = threadIdx.x;
  const int lane = tid & 63;
  const int w = tid >> 6;
  const int quad = lane >> 4;
  const int l15 = lane & 15;
  const int rowBase = blockIdx.x * 64;

  for (int i = tid; i < 48 * 64; i += 256) {
    int n = i >> 6;
    int k = i & 63;
    w2t[n * AP + k] = (n < NCLS) ? f2bf(W2[(size_t)k * NCLS + n]) : (unsigned short)0;
  }
#pragma unroll
  for (int i = 0; i < 2; ++i) {
    int f = tid + 256 * i;        // 512 short8 groups
    int r = f >> 3;
    int q = f & 7;
    int gr = rowBase + r;
    short8 v = (short8){0, 0, 0, 0, 0, 0, 0, 0};
    if (gr < N_NODES) v = *(const short8*)&ab[(size_t)gr * HID + q * 8];
    *(short8*)&as[r * AP + q * 8] = v;
  }
  __syncthreads();

  floatx4 acc[3];
#pragma unroll
  for (int c = 0; c < 3; ++c) acc[c] = (floatx4){0.f, 0.f, 0.f, 0.f};

#pragma unroll
  for (int kh = 0; kh < 2; ++kh) {
    const short8 a = *(const short8*)&as[(w * 16 + l15) * AP + kh * 32 + quad * 8];
#pragma unroll
    for (int c = 0; c < 3; ++c) {
      const short8 b = *(const short8*)&w2t[(c * 16 + l15) * AP + kh * 32 + quad * 8];
      acc[c] = __builtin_amdgcn_mfma_f32_16x16x32_bf16(a, b, acc[c], 0, 0, 0);
    }
  }

#pragma unroll
  for (int reg = 0; reg < 4; ++reg) {
    int gr = rowBase + w * 16 + quad * 4 + reg;
    if (gr < N_NODES) {
      float d = dis[gr];
#pragma unroll
      for (int c = 0; c < 3; ++c) {
        int cc = c * 16 + l15;
        if (cc < NCLS)
          gb[(size_t)gr * 64 + cc] = f2bf(d * acc[c][reg]);
      }
    }
  }
}

// ---------------- agg2 + log_softmax fused ----------------

__global__ __launch_bounds__(256) void k_agg2ls(const int* __restrict__ esrc,
                                                const int* __restrict__ start,
                                                const float* __restrict__ dis,
                                                const unsigned short* __restrict__ gb,
                                                const float* __restrict__ b2,
                                                float* __restrict__ out) {
  int gid = blockIdx.x * 256 + threadIdx.x;
  int node = gid >> 6;
  int lane = gid & 63;
  if (node >= N_NODES) return;
  const bool act = lane < NCLS;
  int s0 = start[node];
  int e0 = start[node + 1];
  float acc = act ? bf2f(gb[(size_t)node * 64 + lane]) : 0.f;  // self (pre-scaled)
  int i = s0;
  for (; i + 8 <= e0; i += 8) {
    int s_[8];
    float hv[8];
#pragma unroll
    for (int j = 0; j < 8; ++j) s_[j] = esrc[i + j];
#pragma unroll
    for (int j = 0; j < 8; ++j) hv[j] = bf2f(gb[(size_t)s_[j] * 64 + lane]);
    float t = 0.f;
#pragma unroll
    for (int j = 0; j < 8; ++j) t += hv[j];
    acc += t;
  }
  for (; i < e0; ++i) acc += bf2f(gb[(size_t)esrc[i] * 64 + lane]);
  float val = act ? dis[node] * acc + b2[lane] : 0.f;
  float m = act ? val : -INFINITY;
#pragma unroll
  for (int off = 32; off > 0; off >>= 1) m = fmaxf(m, __shfl_xor(m, off));
  float ex = act ? expf(val - m) : 0.f;
  float s = ex;
#pragma unroll
  for (int off = 32; off > 0; off >>= 1) s += __shfl_xor(s, off);
  float ls = logf(s);
  if (act) out[(size_t)node * NCLS + lane] = val - m - ls;
}

// ---------------- launch ----------------

extern "C" void kernel_launch(void* const* d_in, const int* in_sizes, int n_in,
                              void* d_out, int out_size, void* d_ws, size_t ws_size,
                              hipStream_t stream) {
  const float* x  = (const float*)d_in[0];
  const int*   ei = (const int*)d_in[1];
  const float* W1 = (const float*)d_in[2];
  const float* b1 = (const float*)d_in[3];
  const float* W2 = (const float*)d_in[4];
  const float* b2 = (const float*)d_in[5];
  float* out = (float*)d_out;

  const int* row = ei;             // edge_index[0] = src
  const int* col = ei + N_EDGES;   // edge_index[1] = dst

  // workspace layout (~41 MB)
  int*            esrc    = (int*)d_ws;                            // E ints     (6.4 MB)
  unsigned int*   bktdata = (unsigned int*)(esrc + N_EDGES);       // NBKT*CAP   (8.0 MB)
  unsigned short* h1b     = (unsigned short*)(bktdata + (size_t)NBKT * BKT_CAP); // 12.8 MB
  unsigned short* ab      = h1b + (size_t)N_NODES * HID;           // N*64 bf16  (12.8 MB)
  float*          dis     = (float*)(ab + (size_t)N_NODES * HID);  // N
  int*            degi    = (int*)(dis + N_NODES);                 // N
  int*            start   = degi + N_NODES;                        // N+1
  int*            gcur    = start + N_NODES + 1;                   // NBKT
  int*            bsum    = gcur + NBKT;                           // NB_SCAN
  int*            bsumS   = bsum + NB_SCAN;                        // NB_SCAN
  unsigned short* gb      = h1b;                                   // N*64 bf16, reuse

  k_zero<<<1, 256, 0, stream>>>(gcur, start);
  k_binA<<<(N_EDGES + EPB - 1) / EPB, 256, 0, stream>>>(row, col, gcur, bktdata);
  k_histdis<<<NBKT, 256, 0, stream>>>(gcur, bktdata, degi, dis);
  k_scan1<<<NB_SCAN, 256, 0, stream>>>(degi, start, bsum);
  k_scan2<<<1, 512, 0, stream>>>(bsum, bsumS);
  k_scan3<<<NB_SCAN, 256, 0, stream>>>(start, bsumS);
  k_place<<<NBKT, 256, 0, stream>>>(gcur, bktdata, start, esrc);

  k_gemm1<<<(N_NODES + 63) / 64, 256, 0, stream>>>(x, W1, dis, h1b);
  k_agg1<<<(N_NODES * 64 + 255) / 256, 256, 0, stream>>>(esrc, start, dis, h1b, b1, ab);

  k_gemm2<<<(N_NODES + 63) / 64, 256, 0, stream>>>(ab, W2, dis, gb);
  k_agg2ls<<<(N_NODES * 64 + 255) / 256, 256, 0, stream>>>(esrc, start, dis, gb, b2, out);
}